// Round 2
// baseline (375.606 us; speedup 1.0000x reference)
//
#include <hip/hip_runtime.h>

// SortPooling, two-kernel split:
//   K1 select: one block per graph; stage col-127 keys in LDS, O(n^2) stable
//              descending rank; rank<K writes the GLOBAL row index to d_ws.
//   K2 gather: barrier-free streaming copy; one float4 per thread, 32 lanes
//              per 512B row, fully coalesced on both ends.
//
// B=8192 graphs, n in [32,96] (always >= K), D=128 fp32, K=30.
// out = B x K x 128 fp32 (~126 MB). Roofline ~286 MB total traffic.

#define KSEL   30
#define MAXN   96
#define DIM    128
#define BLOCK  256

__global__ __launch_bounds__(BLOCK) void select_kernel(
    const float* __restrict__ feat,
    const int*   __restrict__ gi,
    int*         __restrict__ selg)   // B*KSEL global row indices (-1 = invalid)
{
    const int b = blockIdx.x;
    const int t = threadIdx.x;

    __shared__ float key[MAXN];
    __shared__ int   sel[KSEL];

    const int start = gi[2 * b];
    const int end   = gi[2 * b + 1];
    int n = end - start;
    if (n > MAXN) n = MAXN;

    if (t < KSEL) sel[t] = -1;                 // only matters if n < K (never here)
    if (t < n)
        key[t] = feat[(size_t)(start + t) * DIM + (DIM - 1)];
    __syncthreads();

    if (t < n) {
        const float ki = key[t];
        int rank = 0;
        #pragma unroll 4
        for (int j = 0; j < n; ++j) {
            const float kj = key[j];
            // stable descending rank: strictly greater, or equal with lower index
            rank += (kj > ki) || (kj == ki && j < t);
        }
        if (rank < KSEL) sel[rank] = start + t;
    }
    __syncthreads();

    if (t < KSEL) selg[b * KSEL + t] = sel[t];
}

__global__ __launch_bounds__(BLOCK) void gather_kernel(
    const float* __restrict__ feat,
    const int*   __restrict__ selg,
    float*       __restrict__ out)
{
    // one float4 per thread; 32 threads cover one 512B row
    const int e   = blockIdx.x * BLOCK + threadIdx.x;
    const int row = e >> 5;                    // output row in [0, B*KSEL)
    const int c   = (e & 31) << 2;             // float offset within row
    const int r   = selg[row];                 // global source row (L2-resident, 1 MB)

    float4 v;
    if (r >= 0) {
        v = *(const float4*)&feat[(size_t)r * DIM + c];
    } else {
        v = make_float4(0.f, 0.f, 0.f, 0.f);
    }
    *(float4*)&out[(size_t)row * DIM + c] = v;
}

extern "C" void kernel_launch(void* const* d_in, const int* in_sizes, int n_in,
                              void* d_out, int out_size, void* d_ws, size_t ws_size,
                              hipStream_t stream) {
    const float* feat = (const float*)d_in[0];
    const int*   gi   = (const int*)d_in[1];   // graph_indexes as int32 (x64 off)
    float*       out  = (float*)d_out;
    int*         selg = (int*)d_ws;            // B*KSEL ints = 0.98 MB scratch

    const int B = in_sizes[1] / 2;             // 8192 graphs

    select_kernel<<<dim3(B), dim3(BLOCK), 0, stream>>>(feat, gi, selg);

    const int total_f4 = B * KSEL * (DIM / 4); // 7,864,320 float4s
    gather_kernel<<<dim3(total_f4 / BLOCK), dim3(BLOCK), 0, stream>>>(feat, selg, out);
}